// Round 15
// baseline (2453.398 us; speedup 1.0000x reference)
//
#include <hip/hip_runtime.h>
#include <cstddef>

// RQ-VAE forward. N=16384, D_IN=2048, H=4096, C=256, K=256.
// Encoder: bf16x3 split (hi/mid/lo) via virtual-K segments (6 products) ==
// f32-grade precision (argmin indices must match np exactly).
// Decoder: plain bf16. Unified 256x256 MFMA GEMM; m201-faithful 4-phase
// schedule per K-tile: {reads -> stage -> counted vmcnt -> barrier ->
// lgkmcnt(0) -> 16 MFMA -> barrier}; vmcnt NEVER drains to 0 mid-loop.

#define NN 16384
#define DIN 2048
#define HH 4096
#define CC 256
#define QRED ((size_t)4096 * 256)
#define NZ 16

typedef unsigned short ushortT;
typedef __attribute__((ext_vector_type(8))) short bf16x8;
typedef __attribute__((ext_vector_type(4))) float f32x4;

__device__ __forceinline__ ushortT f2b(float v) {        // RNE f32 -> bf16 bits
    unsigned int u = __float_as_uint(v);
    return (ushortT)((u + 0x7fffu + ((u >> 16) & 1u)) >> 16);
}
__device__ __forceinline__ float b2f(ushortT s) {
    return __uint_as_float(((unsigned int)s) << 16);
}
__device__ __forceinline__ void split3(float v, ushortT& h, ushortT& m, ushortT& l) {
    h = f2b(v);
    float r1 = v - b2f(h);
    m = f2b(r1);
    l = f2b(r1 - b2f(m));
}

// async global->LDS 16B copy (lds dest: wave-uniform base + lane*16)
__device__ __forceinline__ void gld16(const void* g, void* l) {
    __builtin_amdgcn_global_load_lds(
        (const __attribute__((address_space(1))) unsigned int*)g,
        (__attribute__((address_space(3))) unsigned int*)l,
        16, 0, 0);
}

// ---------- weight transpose + split: W[K,N] f32 -> NP bf16 planes [N,K] ----
template<int NP>
__launch_bounds__(256)
__global__ void tsplit(const float* __restrict__ W,
                       ushortT* __restrict__ T0,
                       ushortT* __restrict__ T1,
                       ushortT* __restrict__ T2,
                       int K, int N)
{
    __shared__ float tile[32][33];
    const int k0 = blockIdx.y * 32, n0 = blockIdx.x * 32;
    const int c = threadIdx.x & 31, r = threadIdx.x >> 5;
    #pragma unroll
    for (int i = 0; i < 4; ++i)
        tile[r + 8*i][c] = W[(size_t)(k0 + r + 8*i) * N + n0 + c];
    __syncthreads();
    #pragma unroll
    for (int i = 0; i < 4; ++i) {
        const int nl = r + 8*i, kl = c;
        float v = tile[kl][nl];
        size_t o = (size_t)(n0 + nl) * K + k0 + kl;
        ushortT h = f2b(v);
        T0[o] = h;
        if (NP > 1) {
            float r1 = v - b2f(h);
            ushortT m = f2b(r1);
            T1[o] = m;
            T2[o] = f2b(r1 - b2f(m));
        }
    }
}

// ---------- split a f32 matrix into 3 bf16 planes (same layout) ----------
__launch_bounds__(256)
__global__ void split_src(const float* __restrict__ X,
                          ushortT* __restrict__ P0, ushortT* __restrict__ P1,
                          ushortT* __restrict__ P2, size_t n4)
{
    for (size_t i = (size_t)blockIdx.x * 256 + threadIdx.x; i < n4;
         i += (size_t)gridDim.x * 256) {
        float4 v = *(const float4*)(X + i * 4);
        ushort4 hv, mv, lv;
        split3(v.x, ((ushortT*)&hv)[0], ((ushortT*)&mv)[0], ((ushortT*)&lv)[0]);
        split3(v.y, ((ushortT*)&hv)[1], ((ushortT*)&mv)[1], ((ushortT*)&lv)[1]);
        split3(v.z, ((ushortT*)&hv)[2], ((ushortT*)&mv)[2], ((ushortT*)&lv)[2]);
        split3(v.w, ((ushortT*)&hv)[3], ((ushortT*)&mv)[3], ((ushortT*)&lv)[3]);
        *(ushort4*)(P0 + i * 4) = hv;
        *(ushort4*)(P1 + i * 4) = mv;
        *(ushort4*)(P2 + i * 4) = lv;
    }
}

// ---------- unified 256x256 MFMA GEMM, m201-faithful 4-phase pipeline ------
// A: planes [rows,K] at Ab + p*aPl; B: planes [N,K] at Bb + p*bPl.
// Virtual K' = NSEG*K; segment s uses planes (PA[s], PB[s]).
// BK=64, 8 waves (2Mx4N), per-wave 128x64 out. LDS 128 KB: 2 bufs x (A+B).
// Stage subtiles (2 gld16 each): S1={B0,B1} S2={B2,B3} S3={A0,A2} S4={A1,A3}.
// Steady-state issue order: S1(t+1)@ph4(t-1), S2(t+1)@ph1(t), S3@ph2, S4@ph3,
// S1(t+2)@ph4(t).  Waits (in-order vmcnt retirement, m135):
//   ph1: vmcnt(4) => S4(t) landed     (newest 4 = S1,S2(t+1))   [guards ph2]
//   ph4: vmcnt(4) => S1-S3(t+1) landed (newest 4 = S4(t+1),S1(t+2)) [guards ph1']
// Tail: vmcnt degrades 4->2->0. Buffer hazards barrier-proven:
//   S1(t+2) writes buf(t)'s B0,B1 — dead after ph3(t)'s barrier2;
//   S2-S4(t+1) write buf^1 regions dead since tile t-1's ph3/ph4 barriers.
// Per phase: {reads -> stage -> [vmcnt] -> barrier -> lgkm(0) -> 16 MFMA
// (setprio) -> barrier}.  Numerics: per-acc-element order kk0,kk1, tiles
// ascending — bit-identical to prior rounds.
// KSH = log2(K/64). NTC = tiles this block computes (split-K chunk if OM==3).
// EPI: 0 none, 1 relu, 2 sigmoid.
// OM: 0 f32 out; 1 3-plane bf16 out (split3, +oPl stride); 2 1-plane bf16;
//     3 f32 split-K partial at Cf + blockIdx.z*oPl (no bias/EPI).
template<int NSEG, int KSH, int NTC, int EPI, int OM>
__launch_bounds__(512, 2)
__global__ void gemm256(const ushortT* __restrict__ Ab, size_t aPl,
                        const ushortT* __restrict__ Bb, size_t bPl,
                        const float* __restrict__ bias,
                        float* __restrict__ Cf,
                        ushortT* __restrict__ Ob, size_t oPl,
                        int N, int K)
{
    __shared__ ushortT sh[65536];            // [buf][A 16384 | B 16384]

    const int t    = threadIdx.x;            // 0..511
    const int lane = t & 63;
    const int wid  = t >> 6;
    const int l15  = lane & 15;
    const int l4   = lane >> 4;
    const int bm   = blockIdx.y * 256;
    const int bn   = blockIdx.x * 256;
    const int wm   = (wid >> 2) * 128;
    const int wn   = (wid & 3) * 64;
    const int t0   = (OM == 3) ? blockIdx.z * NTC : 0;

    constexpr unsigned PA_PACK = 0x210100u;  // {0,0,1,0,1,2}
    constexpr unsigned PB_PACK = 0x012010u;  // {0,1,0,2,1,0}

    // staging map: source col XOR-swizzled; LDS linear dest (rule #21).
    const int trow = t >> 3;                         // 0..63
    const unsigned tcol = (unsigned)(((t & 7) ^ (trow & 7)) * 8);
    unsigned gA[4], gB[4];
    #pragma unroll
    for (int i = 0; i < 4; ++i) {
        gA[i] = (unsigned)(bm + i * 64 + trow) * (unsigned)K + tcol;
        gB[i] = (unsigned)(bn + i * 64 + trow) * (unsigned)K + tcol;
    }
    const int ldsT = t * 8;                          // elems

    // stage one subtile (2 gld16) of tile gtt into buffer `buf`.
    // s: 0 -> B{0,1}; 1 -> B{2,3}; 2 -> A{0,2}; 3 -> A{1,3}
    auto stageS = [&](int buf, int gtt, int s) {
        const int seg = (NSEG > 1) ? (gtt >> KSH) : 0;
        const unsigned kin = ((unsigned)(gtt & ((1 << KSH) - 1))) << 6;
        const unsigned pa = (NSEG > 1) ? ((PA_PACK >> (seg * 4)) & 15u) : 0u;
        const unsigned pb = (NSEG > 1) ? ((PB_PACK >> (seg * 4)) & 15u) : 0u;
        const ushortT* Abase = Ab + (size_t)pa * aPl + kin;
        const ushortT* Bbase = Bb + (size_t)pb * bPl + kin;
        ushortT* lb = sh + buf * 32768;
        if (s == 0) {
            gld16(Bbase + gB[0], lb + 16384 + 0 * 4096 + ldsT);
            gld16(Bbase + gB[1], lb + 16384 + 1 * 4096 + ldsT);
        } else if (s == 1) {
            gld16(Bbase + gB[2], lb + 16384 + 2 * 4096 + ldsT);
            gld16(Bbase + gB[3], lb + 16384 + 3 * 4096 + ldsT);
        } else if (s == 2) {
            gld16(Abase + gA[0], lb + 0 * 4096 + ldsT);
            gld16(Abase + gA[2], lb + 2 * 4096 + ldsT);
        } else {
            gld16(Abase + gA[1], lb + 1 * 4096 + ldsT);
            gld16(Abase + gA[3], lb + 3 * 4096 + ldsT);
        }
    };

    f32x4 acc[8][4] = {};

    // ---- prologue: S1-S4(t0) + S1(t1); guard S1-S3(t0) ----
    stageS(0, t0, 0);
    stageS(0, t0, 1);
    stageS(0, t0, 2);
    stageS(0, t0, 3);
    if (NTC > 1) {
        stageS(1, t0 + 1, 0);
        asm volatile("s_waitcnt vmcnt(4)" ::: "memory");
    } else {
        asm volatile("s_waitcnt vmcnt(2)" ::: "memory");
    }
    __builtin_amdgcn_sched_barrier(0);
    __builtin_amdgcn_s_barrier();
    __builtin_amdgcn_sched_barrier(0);

    #pragma unroll 1
    for (int tt = 0; tt < NTC; ++tt) {
        const int buf = tt & 1;
        const ushortT* As = sh + buf * 32768;
        const ushortT* Bs = As + 16384;
        const bool h1 = (tt + 1 < NTC);
        const bool h2 = (tt + 2 < NTC);
        bf16x8 b0[4], a0[4], a1[4], b1[4], a2[4], a3[4];

        // ===== ph1 (q0: kk0, mi 0-3) =====
        #pragma unroll
        for (int ni = 0; ni < 4; ++ni) {
            const int rb = wn + ni * 16 + l15;
            b0[ni] = *(const bf16x8*)&Bs[rb * 64 + (l4 ^ (rb & 7)) * 8];
        }
        #pragma unroll
        for (int mi = 0; mi < 4; ++mi) {
            const int ra = wm + mi * 16 + l15;
            a0[mi] = *(const bf16x8*)&As[ra * 64 + (l4 ^ (ra & 7)) * 8];
        }
        if (h1) stageS(buf ^ 1, t0 + tt + 1, 1);      // S2(t+1)
        if (h1) { asm volatile("s_waitcnt vmcnt(4)" ::: "memory"); }
        else    { asm volatile("s_waitcnt vmcnt(0)" ::: "memory"); }
        __builtin_amdgcn_sched_barrier(0);
        __builtin_amdgcn_s_barrier();
        asm volatile("s_waitcnt lgkmcnt(0)" ::: "memory");
        __builtin_amdgcn_sched_barrier(0);
        __builtin_amdgcn_s_setprio(1);
        #pragma unroll
        for (int mi = 0; mi < 4; ++mi)
            #pragma unroll
            for (int ni = 0; ni < 4; ++ni)
                acc[mi][ni] = __builtin_amdgcn_mfma_f32_16x16x32_bf16(
                    a0[mi], b0[ni], acc[mi][ni], 0, 0, 0);
        __builtin_amdgcn_s_setprio(0);
        __builtin_amdgcn_sched_barrier(0);
        __builtin_amdgcn_s_barrier();
        __builtin_amdgcn_sched_barrier(0);

        // ===== ph2 (q1: kk0, mi 4-7) =====
        #pragma unroll
        for (int mi = 0; mi < 4; ++mi) {
            const int ra = wm + (mi + 4) * 16 + l15;
            a1[mi] = *(const bf16x8*)&As[ra * 64 + (l4 ^ (ra & 7)) * 8];
        }
        if (h1) stageS(buf ^ 1, t0 + tt + 1, 2);      // S3(t+1)
        __builtin_amdgcn_sched_barrier(0);
        __builtin_amdgcn_s_barrier();
        asm volatile("s_waitcnt lgkmcnt(0)" ::: "memory");
        __builtin_amdgcn_sched_barrier(0);
        __builtin_amdgcn_s_setprio(1);
        #pragma unroll
        for (int mi = 0; mi < 4; ++mi)
            #pragma unroll
            for (int ni = 0; ni < 4; ++ni)
                acc[mi + 4][ni] = __builtin_amdgcn_mfma_f32_16x16x32_bf16(
                    a1[mi], b0[ni], acc[mi + 4][ni], 0, 0, 0);
        __builtin_amdgcn_s_setprio(0);
        __builtin_amdgcn_sched_barrier(0);
        __builtin_amdgcn_s_barrier();
        __builtin_amdgcn_sched_barrier(0);

        // ===== ph3 (q2: kk1, mi 0-3) =====
        #pragma unroll
        for (int ni = 0; ni < 4; ++ni) {
            const int rb = wn + ni * 16 + l15;
            b1[ni] = *(const bf16x8*)&Bs[rb * 64 + ((4 | l4) ^ (rb & 7)) * 8];
        }
        #pragma unroll
        for (int mi = 0; mi < 4; ++mi) {
            const int ra = wm + mi * 16 + l15;
            a2[mi] = *(const bf16x8*)&As[ra * 64 + ((4 | l4) ^ (ra & 7)) * 8];
        }
        if (h1) stageS(buf ^ 1, t0 + tt + 1, 3);      // S4(t+1)
        __builtin_amdgcn_sched_barrier(0);
        __builtin_amdgcn_s_barrier();
        asm volatile("s_waitcnt lgkmcnt(0)" ::: "memory");
        __builtin_amdgcn_sched_barrier(0);
        __builtin_amdgcn_s_setprio(1);
        #pragma unroll
        for (int mi = 0; mi < 4; ++mi)
            #pragma unroll
            for (int ni = 0; ni < 4; ++ni)
                acc[mi][ni] = __builtin_amdgcn_mfma_f32_16x16x32_bf16(
                    a2[mi], b1[ni], acc[mi][ni], 0, 0, 0);
        __builtin_amdgcn_s_setprio(0);
        __builtin_amdgcn_sched_barrier(0);
        __builtin_amdgcn_s_barrier();
        __builtin_amdgcn_sched_barrier(0);

        // ===== ph4 (q3: kk1, mi 4-7) =====
        #pragma unroll
        for (int mi = 0; mi < 4; ++mi) {
            const int ra = wm + (mi + 4) * 16 + l15;
            a3[mi] = *(const bf16x8*)&As[ra * 64 + ((4 | l4) ^ (ra & 7)) * 8];
        }
        if (h2) stageS(buf, t0 + tt + 2, 0);          // S1(t+2) into buf(t)
        if (h2)      { asm volatile("s_waitcnt vmcnt(4)" ::: "memory"); }
        else if (h1) { asm volatile("s_waitcnt vmcnt(2)" ::: "memory"); }
        else         { asm volatile("s_waitcnt vmcnt(0)" ::: "memory"); }
        __builtin_amdgcn_sched_barrier(0);
        __builtin_amdgcn_s_barrier();
        asm volatile("s_waitcnt lgkmcnt(0)" ::: "memory");
        __builtin_amdgcn_sched_barrier(0);
        __builtin_amdgcn_s_setprio(1);
        #pragma unroll
        for (int mi = 0; mi < 4; ++mi)
            #pragma unroll
            for (int ni = 0; ni < 4; ++ni)
                acc[mi + 4][ni] = __builtin_amdgcn_mfma_f32_16x16x32_bf16(
                    a3[mi], b1[ni], acc[mi + 4][ni], 0, 0, 0);
        __builtin_amdgcn_s_setprio(0);
        __builtin_amdgcn_sched_barrier(0);
        __builtin_amdgcn_s_barrier();
        __builtin_amdgcn_sched_barrier(0);
    }

    // ---- epilogue ----  C/D layout: col = lane&15, row = (lane>>4)*4 + reg
    #pragma unroll
    for (int ni = 0; ni < 4; ++ni) {
        const int gcol = bn + wn + ni * 16 + l15;
        float bvv = 0.0f;
        if (OM != 3) bvv = bias[gcol];
        #pragma unroll
        for (int mi = 0; mi < 8; ++mi) {
            #pragma unroll
            for (int r = 0; r < 4; ++r) {
                const int grow = bm + wm + mi * 16 + l4 * 4 + r;
                const size_t o = (size_t)grow * N + gcol;
                if (OM == 3) {
                    Cf[(size_t)blockIdx.z * oPl + o] = acc[mi][ni][r];
                } else {
                    float v = acc[mi][ni][r] + bvv;
                    if (EPI == 1) v = fmaxf(v, 0.0f);
                    if (EPI == 2) v = 1.0f / (1.0f + expf(-v));
                    if (OM == 0) {
                        Cf[o] = v;
                    } else if (OM == 2) {
                        Ob[o] = f2b(v);
                    } else {
                        ushortT hh, mm, ll;
                        split3(v, hh, mm, ll);
                        Ob[o] = hh; Ob[oPl + o] = mm; Ob[2 * oPl + o] = ll;
                    }
                }
            }
        }
    }
}

// ---------- split-K reduce: out = sum_z part[z] + bias (fixed order) --------
__launch_bounds__(256)
__global__ void reduce_z(const float* __restrict__ part,
                         const float* __restrict__ bias,
                         float* __restrict__ outp, int n4)
{
    const int i = blockIdx.x * 256 + threadIdx.x;
    if (i >= n4) return;
    float4 s = *(const float4*)(part + (size_t)i * 4);
    #pragma unroll
    for (int z = 1; z < NZ; ++z) {
        float4 p = *(const float4*)(part + (size_t)z * (QRED) + (size_t)i * 4);
        s.x = __fadd_rn(s.x, p.x); s.y = __fadd_rn(s.y, p.y);
        s.z = __fadd_rn(s.z, p.z); s.w = __fadd_rn(s.w, p.w);
    }
    const int c4 = (i * 4) & 255;
    float4 b = *(const float4*)(bias + c4);
    s.x = __fadd_rn(s.x, b.x); s.y = __fadd_rn(s.y, b.y);
    s.z = __fadd_rn(s.z, b.z); s.w = __fadd_rn(s.w, b.w);
    *(float4*)(outp + (size_t)i * 4) = s;
}

// ---------------- VQ chain: 3 residual stages, 16 rows/block ----------------
__launch_bounds__(256)
__global__ void vq_kernel(const float* __restrict__ ze1,
                          const float* __restrict__ cb1,
                          const float* __restrict__ cb2,
                          const float* __restrict__ cb3,
                          float* __restrict__ out_ze2, float* __restrict__ out_ze3,
                          float* __restrict__ out_zq1, float* __restrict__ out_zq2,
                          float* __restrict__ out_zq3,
                          float* __restrict__ out_n1,  float* __restrict__ out_n2,
                          float* __restrict__ out_n3,
                          ushortT* __restrict__ dec_p)
{
    __shared__ float Zs[16][260];
    __shared__ float Ds[16][260];
    __shared__ float DecS[16][260];
    __shared__ float Srow[16];
    __shared__ int   Kmin[16];

    const int t    = threadIdx.x;
    const int row0 = blockIdx.x * 16;

    for (int i = t; i < 16*64; i += 256) {
        int r = i >> 6, c4 = (i & 63) << 2;
        float4 v = *(const float4*)(ze1 + (size_t)(row0 + r) * 256 + c4);
        *(float4*)&Zs[r][c4] = v;
        float4 z = {0.f,0.f,0.f,0.f};
        *(float4*)&DecS[r][c4] = z;
    }
    __syncthreads();

    const float* cbs[3] = {cb1, cb2, cb3};
    float* zqs[3] = {out_zq1, out_zq2, out_zq3};
    float* nss[3] = {out_n1, out_n2, out_n3};

    for (int s = 0; s < 3; ++s) {
        const float* cb = cbs[s];
        if (t < 16) {
            float ssum = 0.f;
            for (int c = 0; c < 256; ++c) ssum = fmaf(Zs[t][c], Zs[t][c], ssum);
            Srow[t] = ssum;
        }
        __syncthreads();
        {
            float accr[16];
            #pragma unroll
            for (int r = 0; r < 16; ++r) accr[r] = 0.f;
            float c2 = 0.f;
            const float* cbrow = cb + (size_t)t * 256;
            for (int c4 = 0; c4 < 256; c4 += 4) {
                float4 cv = *(const float4*)(cbrow + c4);
                c2 = fmaf(cv.x,cv.x,fmaf(cv.y,cv.y,fmaf(cv.z,cv.z,fmaf(cv.w,cv.w,c2))));
                #pragma unroll
                for (int r = 0; r < 16; ++r) {
                    float4 zv = *(const float4*)&Zs[r][c4];
                    accr[r] = fmaf(zv.x,cv.x,fmaf(zv.y,cv.y,
                              fmaf(zv.z,cv.z,fmaf(zv.w,cv.w,accr[r]))));
                }
            }
            #pragma unroll
            for (int r = 0; r < 16; ++r) {
                float g2 = __fmul_rn(2.0f, accr[r]);
                float t1 = __fsub_rn(Srow[r], g2);
                Ds[r][t]  = __fadd_rn(t1, c2);
            }
        }
        __syncthreads();
        if (t < 16) {
            float best = Ds[t][0];
            int bk = 0;
            for (int k = 1; k < 256; ++k) {
                float v = Ds[t][k];
                if (v < best) { best = v; bk = k; }
            }
            Kmin[t] = bk;
            nss[s][row0 + t] = (float)bk;
        }
        __syncthreads();
        for (int i = t; i < 16*64; i += 256) {
            int r = i >> 6, c4 = (i & 63) << 2;
            const float* q = cb + (size_t)Kmin[r] * 256 + c4;
            float4 qv = *(const float4*)q;
            *(float4*)&zqs[s][(size_t)(row0 + r) * 256 + c4] = qv;
            float4 dv = *(float4*)&DecS[r][c4];
            dv.x = __fadd_rn(dv.x, qv.x); dv.y = __fadd_rn(dv.y, qv.y);
            dv.z = __fadd_rn(dv.z, qv.z); dv.w = __fadd_rn(dv.w, qv.w);
            *(float4*)&DecS[r][c4] = dv;
            if (s < 2) {
                float4 zv = *(float4*)&Zs[r][c4];
                zv.x = __fsub_rn(zv.x, qv.x); zv.y = __fsub_rn(zv.y, qv.y);
                zv.z = __fsub_rn(zv.z, qv.z); zv.w = __fsub_rn(zv.w, qv.w);
                *(float4*)&Zs[r][c4] = zv;
                float* oz = (s == 0) ? out_ze2 : out_ze3;
                *(float4*)&oz[(size_t)(row0 + r) * 256 + c4] = zv;
            }
        }
        __syncthreads();
    }

    for (int i = t; i < 16*64; i += 256) {
        int r = i >> 6, c4 = (i & 63) << 2;
        float4 z1 = *(const float4*)(ze1 + (size_t)(row0 + r) * 256 + c4);
        float4 dv = *(float4*)&DecS[r][c4];
        float4 o;
        o.x = __fadd_rn(z1.x, __fsub_rn(dv.x, z1.x));
        o.y = __fadd_rn(z1.y, __fsub_rn(dv.y, z1.y));
        o.z = __fadd_rn(z1.z, __fsub_rn(dv.z, z1.z));
        o.w = __fadd_rn(z1.w, __fsub_rn(dv.w, z1.w));
        ushort4 ov;
        ((ushortT*)&ov)[0] = f2b(o.x);
        ((ushortT*)&ov)[1] = f2b(o.y);
        ((ushortT*)&ov)[2] = f2b(o.z);
        ((ushortT*)&ov)[3] = f2b(o.w);
        *(ushort4*)(dec_p + (size_t)(row0 + r) * 256 + c4) = ov;
    }
}

extern "C" void kernel_launch(void* const* d_in, const int* in_sizes, int n_in,
                              void* d_out, int out_size, void* d_ws, size_t ws_size,
                              hipStream_t stream)
{
    const float* x   = (const float*)d_in[0];
    const float* We1 = (const float*)d_in[1];
    const float* be1 = (const float*)d_in[2];
    const float* We2 = (const float*)d_in[3];
    const float* be2 = (const float*)d_in[4];
    const float* cb1 = (const float*)d_in[5];
    const float* cb2 = (const float*)d_in[6];
    const float* cb3 = (const float*)d_in[7];
    const float* Wd1 = (const float*)d_in[8];
    const float* bd1 = (const float*)d_in[9];
    const float* Wd2 = (const float*)d_in[10];
    const float* bd2 = (const float*)d_in[11];

    float* out   = (float*)d_out;
    float* x_hat = out;
    float* ze1   = out + 33554432;
    float* ze2   = out + 37748736;
    float* ze3   = out + 41943040;
    float* zq1   = out + 46137344;
    float* zq2   = out + 50331648;
    float* zq3   = out + 54525952;
    float* n1    = out + 58720256;
    float* n2    = out + 58736640;
    float* n3    = out + 58753024;

    const int    QR   = 4096;                 // quarter rows
    const size_t szXq = (size_t)QR * DIN;     // 8.39M
    const size_t szHq = (size_t)QR * HH;      // 16.8M
    const size_t szW1 = (size_t)HH * DIN;     // 8.39M
    const size_t szW2 = (size_t)CC * HH;      // 1.05M

    // ws layout (ushort elems), peak ~300 MB (< 336 proven in R8):
    ushortT* xq   = (ushortT*)d_ws;           // 3 planes [QR,DIN]
    ushortT* hq   = xq + 3 * szXq;            // 3 planes [QR,HH]
    ushortT* We1t = hq + 3 * szHq;            // 3 planes [HH,DIN]
    ushortT* We2t = We1t + 3 * szW1;          // 3 planes [CC,HH]
    ushortT* Wd1t = We2t + 3 * szW2;          // 1 plane  [HH,CC]
    ushortT* Wd2t = Wd1t + szW2;              // 1 plane  [DIN,HH]
    ushortT* decp = Wd2t + szW1;              // [NN,CC] bf16
    float*   zpart = (float*)(decp + (size_t)NN * CC);   // [NZ][QR*CC] f32
    ushortT* h2p  = xq;                       // overlay: [NN,HH] bf16

    dim3 blk(256), blk5(512);

    tsplit<3><<<dim3(HH/32, DIN/32), blk, 0, stream>>>(We1, We1t, We1t+szW1, We1t+2*szW1, DIN, HH);
    tsplit<3><<<dim3(CC/32, HH/32),  blk, 0, stream>>>(We2, We2t, We2t+szW2, We2t+2*szW2, HH, CC);
    tsplit<1><<<dim3(HH/32, CC/32),  blk, 0, stream>>>(Wd1, Wd1t, nullptr, nullptr, CC, HH);
    tsplit<1><<<dim3(DIN/32, HH/32), blk, 0, stream>>>(Wd2, Wd2t, nullptr, nullptr, HH, DIN);

    for (int q = 0; q < 4; ++q) {
        split_src<<<dim3(2048), blk, 0, stream>>>(x + (size_t)q * szXq,
                                                  xq, xq + szXq, xq + 2*szXq, szXq / 4);
        // h_q = relu(x_q @ W_e1 + b_e1) -> 3 bf16 planes.  K'=6*2048, NT=192
        gemm256<6,5,192,1,1><<<dim3(HH/256, QR/256), blk5, 0, stream>>>(
            xq, szXq, We1t, szW1, be1, nullptr, hq, szHq, HH, DIN);
        // ze1_q partials: K'=6*4096 = 384 tiles split into NZ=16 chunks of 24
        gemm256<6,6,24,0,3><<<dim3(CC/256, QR/256, NZ), blk5, 0, stream>>>(
            hq, szHq, We2t, szW2, nullptr, zpart, nullptr, QRED, CC, HH);
        reduce_z<<<dim3(QR*CC/4/256), blk, 0, stream>>>(
            zpart, be2, ze1 + (size_t)q * QR * CC, QR*CC/4);
    }

    vq_kernel<<<dim3(NN/16), blk, 0, stream>>>(ze1, cb1, cb2, cb3,
                                               ze2, ze3, zq1, zq2, zq3,
                                               n1, n2, n3, decp);

    // h2 = sigmoid(dec @ W_d1 + b_d1) -> bf16 plane. K=256, NT=4
    gemm256<1,2,4,2,2><<<dim3(HH/256, NN/256), blk5, 0, stream>>>(
        decp, 0, Wd1t, 0, bd1, nullptr, h2p, 0, HH, CC);
    // x_hat = h2 @ W_d2 + b_d2 -> f32. K=4096, NT=64
    gemm256<1,6,64,0,0><<<dim3(DIN/256, NN/256), blk5, 0, stream>>>(
        h2p, 0, Wd2t, 0, bd2, x_hat, nullptr, 0, DIN, HH);
}

// Round 16
// 2338.468 us; speedup vs baseline: 1.0491x; 1.0491x over previous
//
#include <hip/hip_runtime.h>
#include <cstddef>

// RQ-VAE forward. N=16384, D_IN=2048, H=4096, C=256, K=256.
// Encoder: bf16x3 split (hi/mid/lo) via virtual-K segments (6 products) ==
// f32-grade precision (argmin indices must match np exactly).
// Decoder: plain bf16. Unified 256x256 MFMA GEMM; tile body is a 4-phase
// software-pipelined schedule: 2 barriers/tile, ds_reads of phase k+1 issued
// under phase k's MFMA cluster. (r8/r14 champion schedule; G2 split-K NZ=16.)
// NOTE: nine schedule variants benched (r7-r15); this loose 2-barrier form
// is the measured optimum (G1 381us, MfmaUtil 49%). Phased/counted/occupancy
// variants all regressed — pipes sum on this kernel regardless of schedule.

#define NN 16384
#define DIN 2048
#define HH 4096
#define CC 256
#define QRED ((size_t)4096 * 256)
#define NZ 16

typedef unsigned short ushortT;
typedef __attribute__((ext_vector_type(8))) short bf16x8;
typedef __attribute__((ext_vector_type(4))) float f32x4;

__device__ __forceinline__ ushortT f2b(float v) {        // RNE f32 -> bf16 bits
    unsigned int u = __float_as_uint(v);
    return (ushortT)((u + 0x7fffu + ((u >> 16) & 1u)) >> 16);
}
__device__ __forceinline__ float b2f(ushortT s) {
    return __uint_as_float(((unsigned int)s) << 16);
}
__device__ __forceinline__ void split3(float v, ushortT& h, ushortT& m, ushortT& l) {
    h = f2b(v);
    float r1 = v - b2f(h);
    m = f2b(r1);
    l = f2b(r1 - b2f(m));
}

// async global->LDS 16B copy (lds dest: wave-uniform base + lane*16)
__device__ __forceinline__ void gld16(const void* g, void* l) {
    __builtin_amdgcn_global_load_lds(
        (const __attribute__((address_space(1))) unsigned int*)g,
        (__attribute__((address_space(3))) unsigned int*)l,
        16, 0, 0);
}

// ---------- weight transpose + split: W[K,N] f32 -> NP bf16 planes [N,K] ----
template<int NP>
__launch_bounds__(256)
__global__ void tsplit(const float* __restrict__ W,
                       ushortT* __restrict__ T0,
                       ushortT* __restrict__ T1,
                       ushortT* __restrict__ T2,
                       int K, int N)
{
    __shared__ float tile[32][33];
    const int k0 = blockIdx.y * 32, n0 = blockIdx.x * 32;
    const int c = threadIdx.x & 31, r = threadIdx.x >> 5;
    #pragma unroll
    for (int i = 0; i < 4; ++i)
        tile[r + 8*i][c] = W[(size_t)(k0 + r + 8*i) * N + n0 + c];
    __syncthreads();
    #pragma unroll
    for (int i = 0; i < 4; ++i) {
        const int nl = r + 8*i, kl = c;
        float v = tile[kl][nl];
        size_t o = (size_t)(n0 + nl) * K + k0 + kl;
        ushortT h = f2b(v);
        T0[o] = h;
        if (NP > 1) {
            float r1 = v - b2f(h);
            ushortT m = f2b(r1);
            T1[o] = m;
            T2[o] = f2b(r1 - b2f(m));
        }
    }
}

// ---------- split a f32 matrix into 3 bf16 planes (same layout) ----------
__launch_bounds__(256)
__global__ void split_src(const float* __restrict__ X,
                          ushortT* __restrict__ P0, ushortT* __restrict__ P1,
                          ushortT* __restrict__ P2, size_t n4)
{
    for (size_t i = (size_t)blockIdx.x * 256 + threadIdx.x; i < n4;
         i += (size_t)gridDim.x * 256) {
        float4 v = *(const float4*)(X + i * 4);
        ushort4 hv, mv, lv;
        split3(v.x, ((ushortT*)&hv)[0], ((ushortT*)&mv)[0], ((ushortT*)&lv)[0]);
        split3(v.y, ((ushortT*)&hv)[1], ((ushortT*)&mv)[1], ((ushortT*)&lv)[1]);
        split3(v.z, ((ushortT*)&hv)[2], ((ushortT*)&mv)[2], ((ushortT*)&lv)[2]);
        split3(v.w, ((ushortT*)&hv)[3], ((ushortT*)&mv)[3], ((ushortT*)&lv)[3]);
        *(ushort4*)(P0 + i * 4) = hv;
        *(ushort4*)(P1 + i * 4) = mv;
        *(ushort4*)(P2 + i * 4) = lv;
    }
}

// ---------- unified 256x256 MFMA GEMM, pipelined 4-phase tile body ----------
// A: planes [rows,K] at Ab + p*aPl; B: planes [N,K] at Bb + p*bPl.
// Virtual K' = NSEG*K; segment s uses planes (PA[s], PB[s]).
// BK=64, 8 waves (2Mx4N), per-wave 128x64 out. LDS 128 KB: 2 bufs x (A+B).
// Tile body: vmcnt(0)+barrier (data ready) -> loads(ph0,ph1) -> MFMA0 ->
// stage half -> loads(ph2) -> MFMA1 -> stage half -> loads(ph3) -> MFMA2 ->
// MFMA3 -> barrier (readers done). Next-phase ds_reads fly under MFMAs.
// KSH = log2(K/64). NTC = tiles this block computes (split-K chunk if OM==3).
// EPI: 0 none, 1 relu, 2 sigmoid.
// OM: 0 f32 out; 1 3-plane bf16 out (split3, +oPl stride); 2 1-plane bf16;
//     3 f32 split-K partial at Cf + blockIdx.z*oPl (no bias/EPI).
template<int NSEG, int KSH, int NTC, int EPI, int OM>
__launch_bounds__(512, 2)
__global__ void gemm256(const ushortT* __restrict__ Ab, size_t aPl,
                        const ushortT* __restrict__ Bb, size_t bPl,
                        const float* __restrict__ bias,
                        float* __restrict__ Cf,
                        ushortT* __restrict__ Ob, size_t oPl,
                        int N, int K)
{
    __shared__ ushortT sh[65536];            // [buf][A 16384 | B 16384]

    const int t    = threadIdx.x;            // 0..511
    const int lane = t & 63;
    const int wid  = t >> 6;
    const int l15  = lane & 15;
    const int l4   = lane >> 4;
    const int bm   = blockIdx.y * 256;
    const int bn   = blockIdx.x * 256;
    const int wm   = (wid >> 2) * 128;
    const int wn   = (wid & 3) * 64;
    const int t0   = (OM == 3) ? blockIdx.z * NTC : 0;

    constexpr unsigned PA_PACK = 0x210100u;  // {0,0,1,0,1,2}
    constexpr unsigned PB_PACK = 0x012010u;  // {0,1,0,2,1,0}

    // staging map: source col XOR-swizzled; LDS linear dest (rule #21).
    const int trow = t >> 3;                         // 0..63
    const unsigned tcol = (unsigned)(((t & 7) ^ (trow & 7)) * 8);
    unsigned gA[4], gB[4];
    #pragma unroll
    for (int i = 0; i < 4; ++i) {
        gA[i] = (unsigned)(bm + i * 64 + trow) * (unsigned)K + tcol;
        gB[i] = (unsigned)(bn + i * 64 + trow) * (unsigned)K + tcol;
    }
    const int ldsT = t * 8;                          // elems

    // stage one half (4 gld16) of tile gtt into buffer `buf`.
    auto stageH = [&](int buf, int gtt, int half) {
        const int seg = (NSEG > 1) ? (gtt >> KSH) : 0;
        const unsigned kin = ((unsigned)(gtt & ((1 << KSH) - 1))) << 6;
        const unsigned pa = (NSEG > 1) ? ((PA_PACK >> (seg * 4)) & 15u) : 0u;
        const unsigned pb = (NSEG > 1) ? ((PB_PACK >> (seg * 4)) & 15u) : 0u;
        const ushortT* Abase = Ab + (size_t)pa * aPl + kin;
        const ushortT* Bbase = Bb + (size_t)pb * bPl + kin;
        ushortT* lb = sh + buf * 32768;
        if (half == 0) {
            gld16(Abase + gA[0], lb + 0 * 4096 + ldsT);
            gld16(Abase + gA[2], lb + 2 * 4096 + ldsT);
            gld16(Bbase + gB[0], lb + 16384 + 0 * 4096 + ldsT);
            gld16(Bbase + gB[1], lb + 16384 + 1 * 4096 + ldsT);
        } else {
            gld16(Bbase + gB[2], lb + 16384 + 2 * 4096 + ldsT);
            gld16(Bbase + gB[3], lb + 16384 + 3 * 4096 + ldsT);
            gld16(Abase + gA[1], lb + 1 * 4096 + ldsT);
            gld16(Abase + gA[3], lb + 3 * 4096 + ldsT);
        }
    };

    f32x4 acc[8][4] = {};

    stageH(0, t0, 0);
    stageH(0, t0, 1);

    #pragma unroll 1
    for (int tt = 0; tt < NTC; ++tt) {
        const int buf = tt & 1;
        const ushortT* As = sh + buf * 32768;
        const ushortT* Bs = As + 16384;
        const bool notlast = (tt + 1 < NTC);
        bf16x8 b0[4], a0[4], a1[4], b1[4], a2[4], a3[4];

        // ---- data-ready rendezvous ----
        asm volatile("s_waitcnt vmcnt(0)" ::: "memory");
        __builtin_amdgcn_sched_barrier(0);
        __builtin_amdgcn_s_barrier();
        __builtin_amdgcn_sched_barrier(0);

        // ---- loads for ph0 + ph1 (kk=0) ----
        #pragma unroll
        for (int ni = 0; ni < 4; ++ni) {
            const int rb = wn + ni * 16 + l15;
            b0[ni] = *(const bf16x8*)&Bs[rb * 64 + (l4 ^ (rb & 7)) * 8];
        }
        #pragma unroll
        for (int mi = 0; mi < 4; ++mi) {
            const int ra = wm + mi * 16 + l15;
            a0[mi] = *(const bf16x8*)&As[ra * 64 + (l4 ^ (ra & 7)) * 8];
        }
        #pragma unroll
        for (int mi = 0; mi < 4; ++mi) {
            const int ra = wm + (mi + 4) * 16 + l15;
            a1[mi] = *(const bf16x8*)&As[ra * 64 + (l4 ^ (ra & 7)) * 8];
        }
        // ---- MFMA ph0 ----
        __builtin_amdgcn_s_setprio(1);
        #pragma unroll
        for (int mi = 0; mi < 4; ++mi)
            #pragma unroll
            for (int ni = 0; ni < 4; ++ni)
                acc[mi][ni] = __builtin_amdgcn_mfma_f32_16x16x32_bf16(
                    a0[mi], b0[ni], acc[mi][ni], 0, 0, 0);
        __builtin_amdgcn_s_setprio(0);
        __builtin_amdgcn_sched_barrier(0);
        if (notlast) stageH(buf ^ 1, t0 + tt + 1, 0);
        // ---- loads for ph2 (kk=1) ----
        #pragma unroll
        for (int ni = 0; ni < 4; ++ni) {
            const int rb = wn + ni * 16 + l15;
            b1[ni] = *(const bf16x8*)&Bs[rb * 64 + ((4 | l4) ^ (rb & 7)) * 8];
        }
        #pragma unroll
        for (int mi = 0; mi < 4; ++mi) {
            const int ra = wm + mi * 16 + l15;
            a2[mi] = *(const bf16x8*)&As[ra * 64 + ((4 | l4) ^ (ra & 7)) * 8];
        }
        // ---- MFMA ph1 ----
        __builtin_amdgcn_s_setprio(1);
        #pragma unroll
        for (int mi = 0; mi < 4; ++mi)
            #pragma unroll
            for (int ni = 0; ni < 4; ++ni)
                acc[mi + 4][ni] = __builtin_amdgcn_mfma_f32_16x16x32_bf16(
                    a1[mi], b0[ni], acc[mi + 4][ni], 0, 0, 0);
        __builtin_amdgcn_s_setprio(0);
        __builtin_amdgcn_sched_barrier(0);
        if (notlast) stageH(buf ^ 1, t0 + tt + 1, 1);
        // ---- loads for ph3 ----
        #pragma unroll
        for (int mi = 0; mi < 4; ++mi) {
            const int ra = wm + (mi + 4) * 16 + l15;
            a3[mi] = *(const bf16x8*)&As[ra * 64 + ((4 | l4) ^ (ra & 7)) * 8];
        }
        // ---- MFMA ph2 ----
        __builtin_amdgcn_s_setprio(1);
        #pragma unroll
        for (int mi = 0; mi < 4; ++mi)
            #pragma unroll
            for (int ni = 0; ni < 4; ++ni)
                acc[mi][ni] = __builtin_amdgcn_mfma_f32_16x16x32_bf16(
                    a2[mi], b1[ni], acc[mi][ni], 0, 0, 0);
        __builtin_amdgcn_s_setprio(0);
        // ---- MFMA ph3 ----
        __builtin_amdgcn_s_setprio(1);
        #pragma unroll
        for (int mi = 0; mi < 4; ++mi)
            #pragma unroll
            for (int ni = 0; ni < 4; ++ni)
                acc[mi + 4][ni] = __builtin_amdgcn_mfma_f32_16x16x32_bf16(
                    a3[mi], b1[ni], acc[mi + 4][ni], 0, 0, 0);
        __builtin_amdgcn_s_setprio(0);
        __builtin_amdgcn_sched_barrier(0);
        // ---- readers-done rendezvous ----
        __builtin_amdgcn_s_barrier();
        __builtin_amdgcn_sched_barrier(0);
    }

    // ---- epilogue ----  C/D layout: col = lane&15, row = (lane>>4)*4 + reg
    #pragma unroll
    for (int ni = 0; ni < 4; ++ni) {
        const int gcol = bn + wn + ni * 16 + l15;
        float bvv = 0.0f;
        if (OM != 3) bvv = bias[gcol];
        #pragma unroll
        for (int mi = 0; mi < 8; ++mi) {
            #pragma unroll
            for (int r = 0; r < 4; ++r) {
                const int grow = bm + wm + mi * 16 + l4 * 4 + r;
                const size_t o = (size_t)grow * N + gcol;
                if (OM == 3) {
                    Cf[(size_t)blockIdx.z * oPl + o] = acc[mi][ni][r];
                } else {
                    float v = acc[mi][ni][r] + bvv;
                    if (EPI == 1) v = fmaxf(v, 0.0f);
                    if (EPI == 2) v = 1.0f / (1.0f + expf(-v));
                    if (OM == 0) {
                        Cf[o] = v;
                    } else if (OM == 2) {
                        Ob[o] = f2b(v);
                    } else {
                        ushortT hh, mm, ll;
                        split3(v, hh, mm, ll);
                        Ob[o] = hh; Ob[oPl + o] = mm; Ob[2 * oPl + o] = ll;
                    }
                }
            }
        }
    }
}

// ---------- split-K reduce: out = sum_z part[z] + bias (fixed order) --------
__launch_bounds__(256)
__global__ void reduce_z(const float* __restrict__ part,
                         const float* __restrict__ bias,
                         float* __restrict__ outp, int n4)
{
    const int i = blockIdx.x * 256 + threadIdx.x;
    if (i >= n4) return;
    float4 s = *(const float4*)(part + (size_t)i * 4);
    #pragma unroll
    for (int z = 1; z < NZ; ++z) {
        float4 p = *(const float4*)(part + (size_t)z * (QRED) + (size_t)i * 4);
        s.x = __fadd_rn(s.x, p.x); s.y = __fadd_rn(s.y, p.y);
        s.z = __fadd_rn(s.z, p.z); s.w = __fadd_rn(s.w, p.w);
    }
    const int c4 = (i * 4) & 255;
    float4 b = *(const float4*)(bias + c4);
    s.x = __fadd_rn(s.x, b.x); s.y = __fadd_rn(s.y, b.y);
    s.z = __fadd_rn(s.z, b.z); s.w = __fadd_rn(s.w, b.w);
    *(float4*)(outp + (size_t)i * 4) = s;
}

// ---------------- VQ chain: 3 residual stages, 16 rows/block ----------------
__launch_bounds__(256)
__global__ void vq_kernel(const float* __restrict__ ze1,
                          const float* __restrict__ cb1,
                          const float* __restrict__ cb2,
                          const float* __restrict__ cb3,
                          float* __restrict__ out_ze2, float* __restrict__ out_ze3,
                          float* __restrict__ out_zq1, float* __restrict__ out_zq2,
                          float* __restrict__ out_zq3,
                          float* __restrict__ out_n1,  float* __restrict__ out_n2,
                          float* __restrict__ out_n3,
                          ushortT* __restrict__ dec_p)
{
    __shared__ float Zs[16][260];
    __shared__ float Ds[16][260];
    __shared__ float DecS[16][260];
    __shared__ float Srow[16];
    __shared__ int   Kmin[16];

    const int t    = threadIdx.x;
    const int row0 = blockIdx.x * 16;

    for (int i = t; i < 16*64; i += 256) {
        int r = i >> 6, c4 = (i & 63) << 2;
        float4 v = *(const float4*)(ze1 + (size_t)(row0 + r) * 256 + c4);
        *(float4*)&Zs[r][c4] = v;
        float4 z = {0.f,0.f,0.f,0.f};
        *(float4*)&DecS[r][c4] = z;
    }
    __syncthreads();

    const float* cbs[3] = {cb1, cb2, cb3};
    float* zqs[3] = {out_zq1, out_zq2, out_zq3};
    float* nss[3] = {out_n1, out_n2, out_n3};

    for (int s = 0; s < 3; ++s) {
        const float* cb = cbs[s];
        if (t < 16) {
            float ssum = 0.f;
            for (int c = 0; c < 256; ++c) ssum = fmaf(Zs[t][c], Zs[t][c], ssum);
            Srow[t] = ssum;
        }
        __syncthreads();
        {
            float accr[16];
            #pragma unroll
            for (int r = 0; r < 16; ++r) accr[r] = 0.f;
            float c2 = 0.f;
            const float* cbrow = cb + (size_t)t * 256;
            for (int c4 = 0; c4 < 256; c4 += 4) {
                float4 cv = *(const float4*)(cbrow + c4);
                c2 = fmaf(cv.x,cv.x,fmaf(cv.y,cv.y,fmaf(cv.z,cv.z,fmaf(cv.w,cv.w,c2))));
                #pragma unroll
                for (int r = 0; r < 16; ++r) {
                    float4 zv = *(const float4*)&Zs[r][c4];
                    accr[r] = fmaf(zv.x,cv.x,fmaf(zv.y,cv.y,
                              fmaf(zv.z,cv.z,fmaf(zv.w,cv.w,accr[r]))));
                }
            }
            #pragma unroll
            for (int r = 0; r < 16; ++r) {
                float g2 = __fmul_rn(2.0f, accr[r]);
                float t1 = __fsub_rn(Srow[r], g2);
                Ds[r][t]  = __fadd_rn(t1, c2);
            }
        }
        __syncthreads();
        if (t < 16) {
            float best = Ds[t][0];
            int bk = 0;
            for (int k = 1; k < 256; ++k) {
                float v = Ds[t][k];
                if (v < best) { best = v; bk = k; }
            }
            Kmin[t] = bk;
            nss[s][row0 + t] = (float)bk;
        }
        __syncthreads();
        for (int i = t; i < 16*64; i += 256) {
            int r = i >> 6, c4 = (i & 63) << 2;
            const float* q = cb + (size_t)Kmin[r] * 256 + c4;
            float4 qv = *(const float4*)q;
            *(float4*)&zqs[s][(size_t)(row0 + r) * 256 + c4] = qv;
            float4 dv = *(float4*)&DecS[r][c4];
            dv.x = __fadd_rn(dv.x, qv.x); dv.y = __fadd_rn(dv.y, qv.y);
            dv.z = __fadd_rn(dv.z, qv.z); dv.w = __fadd_rn(dv.w, qv.w);
            *(float4*)&DecS[r][c4] = dv;
            if (s < 2) {
                float4 zv = *(float4*)&Zs[r][c4];
                zv.x = __fsub_rn(zv.x, qv.x); zv.y = __fsub_rn(zv.y, qv.y);
                zv.z = __fsub_rn(zv.z, qv.z); zv.w = __fsub_rn(zv.w, qv.w);
                *(float4*)&Zs[r][c4] = zv;
                float* oz = (s == 0) ? out_ze2 : out_ze3;
                *(float4*)&oz[(size_t)(row0 + r) * 256 + c4] = zv;
            }
        }
        __syncthreads();
    }

    for (int i = t; i < 16*64; i += 256) {
        int r = i >> 6, c4 = (i & 63) << 2;
        float4 z1 = *(const float4*)(ze1 + (size_t)(row0 + r) * 256 + c4);
        float4 dv = *(float4*)&DecS[r][c4];
        float4 o;
        o.x = __fadd_rn(z1.x, __fsub_rn(dv.x, z1.x));
        o.y = __fadd_rn(z1.y, __fsub_rn(dv.y, z1.y));
        o.z = __fadd_rn(z1.z, __fsub_rn(dv.z, z1.z));
        o.w = __fadd_rn(z1.w, __fsub_rn(dv.w, z1.w));
        ushort4 ov;
        ((ushortT*)&ov)[0] = f2b(o.x);
        ((ushortT*)&ov)[1] = f2b(o.y);
        ((ushortT*)&ov)[2] = f2b(o.z);
        ((ushortT*)&ov)[3] = f2b(o.w);
        *(ushort4*)(dec_p + (size_t)(row0 + r) * 256 + c4) = ov;
    }
}

extern "C" void kernel_launch(void* const* d_in, const int* in_sizes, int n_in,
                              void* d_out, int out_size, void* d_ws, size_t ws_size,
                              hipStream_t stream)
{
    const float* x   = (const float*)d_in[0];
    const float* We1 = (const float*)d_in[1];
    const float* be1 = (const float*)d_in[2];
    const float* We2 = (const float*)d_in[3];
    const float* be2 = (const float*)d_in[4];
    const float* cb1 = (const float*)d_in[5];
    const float* cb2 = (const float*)d_in[6];
    const float* cb3 = (const float*)d_in[7];
    const float* Wd1 = (const float*)d_in[8];
    const float* bd1 = (const float*)d_in[9];
    const float* Wd2 = (const float*)d_in[10];
    const float* bd2 = (const float*)d_in[11];

    float* out   = (float*)d_out;
    float* x_hat = out;
    float* ze1   = out + 33554432;
    float* ze2   = out + 37748736;
    float* ze3   = out + 41943040;
    float* zq1   = out + 46137344;
    float* zq2   = out + 50331648;
    float* zq3   = out + 54525952;
    float* n1    = out + 58720256;
    float* n2    = out + 58736640;
    float* n3    = out + 58753024;

    const int    QR   = 4096;                 // quarter rows
    const size_t szXq = (size_t)QR * DIN;     // 8.39M
    const size_t szHq = (size_t)QR * HH;      // 16.8M
    const size_t szW1 = (size_t)HH * DIN;     // 8.39M
    const size_t szW2 = (size_t)CC * HH;      // 1.05M

    // ws layout (ushort elems), peak ~300 MB (< 336 proven in R8):
    ushortT* xq   = (ushortT*)d_ws;           // 3 planes [QR,DIN]
    ushortT* hq   = xq + 3 * szXq;            // 3 planes [QR,HH]
    ushortT* We1t = hq + 3 * szHq;            // 3 planes [HH,DIN]
    ushortT* We2t = We1t + 3 * szW1;          // 3 planes [CC,HH]
    ushortT* Wd1t = We2t + 3 * szW2;          // 1 plane  [HH,CC]
    ushortT* Wd2t = Wd1t + szW2;              // 1 plane  [DIN,HH]
    ushortT* decp = Wd2t + szW1;              // [NN,CC] bf16
    float*   zpart = (float*)(decp + (size_t)NN * CC);   // [NZ][QR*CC] f32
    ushortT* h2p  = xq;                       // overlay: [NN,HH] bf16

    dim3 blk(256), blk5(512);

    tsplit<3><<<dim3(HH/32, DIN/32), blk, 0, stream>>>(We1, We1t, We1t+szW1, We1t+2*szW1, DIN, HH);
    tsplit<3><<<dim3(CC/32, HH/32),  blk, 0, stream>>>(We2, We2t, We2t+szW2, We2t+2*szW2, HH, CC);
    tsplit<1><<<dim3(HH/32, CC/32),  blk, 0, stream>>>(Wd1, Wd1t, nullptr, nullptr, CC, HH);
    tsplit<1><<<dim3(DIN/32, HH/32), blk, 0, stream>>>(Wd2, Wd2t, nullptr, nullptr, HH, DIN);

    for (int q = 0; q < 4; ++q) {
        split_src<<<dim3(2048), blk, 0, stream>>>(x + (size_t)q * szXq,
                                                  xq, xq + szXq, xq + 2*szXq, szXq / 4);
        // h_q = relu(x_q @ W_e1 + b_e1) -> 3 bf16 planes.  K'=6*2048, NT=192
        gemm256<6,5,192,1,1><<<dim3(HH/256, QR/256), blk5, 0, stream>>>(
            xq, szXq, We1t, szW1, be1, nullptr, hq, szHq, HH, DIN);
        // ze1_q partials: K'=6*4096 = 384 tiles split into NZ=16 chunks of 24
        gemm256<6,6,24,0,3><<<dim3(CC/256, QR/256, NZ), blk5, 0, stream>>>(
            hq, szHq, We2t, szW2, nullptr, zpart, nullptr, QRED, CC, HH);
        reduce_z<<<dim3(QR*CC/4/256), blk, 0, stream>>>(
            zpart, be2, ze1 + (size_t)q * QR * CC, QR*CC/4);
    }

    vq_kernel<<<dim3(NN/16), blk, 0, stream>>>(ze1, cb1, cb2, cb3,
                                               ze2, ze3, zq1, zq2, zq3,
                                               n1, n2, n3, decp);

    // h2 = sigmoid(dec @ W_d1 + b_d1) -> bf16 plane. K=256, NT=4
    gemm256<1,2,4,2,2><<<dim3(HH/256, NN/256), blk5, 0, stream>>>(
        decp, 0, Wd1t, 0, bd1, nullptr, h2p, 0, HH, CC);
    // x_hat = h2 @ W_d2 + b_d2 -> f32. K=4096, NT=64
    gemm256<1,6,64,0,0><<<dim3(DIN/256, NN/256), blk5, 0, stream>>>(
        h2p, 0, Wd2t, 0, bd2, x_hat, nullptr, 0, DIN, HH);
}